// Round 7
// baseline (758.066 us; speedup 1.0000x reference)
//
#include <hip/hip_runtime.h>
#include <hip/hip_fp16.h>
#include <math.h>

#define HD 64
#define EPS 1e-5f
#define BSH 9                   // bucket shift: 512 nodes per bucket
#define BSZ 512
#define T1 16384                // edges per tile in k_bucket
// packing: n <= 131072 (2^17) required: packed = (local_dst<<17) | src

typedef float vf4 __attribute__((ext_vector_type(4)));

__device__ __forceinline__ float atomAddF(float* p, float v) {
    return unsafeAtomicAdd(p, v);   // native global_atomic_add_f32 on gfx950
}

__device__ __forceinline__ void h8_to_f(const uint4 u, float* f) {
    const __half2* h = reinterpret_cast<const __half2*>(&u);
    #pragma unroll
    for (int i = 0; i < 4; ++i) {
        float2 p = __half22float2(h[i]);
        f[2 * i] = p.x; f[2 * i + 1] = p.y;
    }
}

// ---------- CSR build (bucketed counting sort) ----------

__global__ __launch_bounds__(256) void k_bhist(const int* __restrict__ dst,
        int* __restrict__ bcnt, int e) {
    __shared__ int h[256];
    int t = threadIdx.x;
    h[t] = 0;
    __syncthreads();
    for (int i = blockIdx.x * 256 + t; i < e; i += gridDim.x * 256)
        atomicAdd(&h[dst[i] >> BSH], 1);
    __syncthreads();
    if (h[t]) atomicAdd(&bcnt[t], h[t]);
}

__global__ __launch_bounds__(256) void k_bscan(const int* __restrict__ bcnt,
        int* __restrict__ boff, int* __restrict__ gcur,
        int* __restrict__ row_ptr, int nb, int n, int e) {
    __shared__ int sc[256];
    int t = threadIdx.x;
    int v = (t < nb) ? bcnt[t] : 0;
    sc[t] = v;
    __syncthreads();
    int acc = v;
    for (int off = 1; off < 256; off <<= 1) {
        int x = (t >= off) ? sc[t - off] : 0;
        __syncthreads();
        acc += x;
        sc[t] = acc;
        __syncthreads();
    }
    int ex = acc - v;
    boff[t] = ex;                    // thread nb writes boff[nb] = e
    gcur[t] = ex;
    if (t == 0) row_ptr[n] = e;
}

__global__ __launch_bounds__(256) void k_bucket(const int* __restrict__ src,
        const int* __restrict__ dst, int* __restrict__ gcur,
        unsigned* __restrict__ bedges, int e) {
    __shared__ int hist[256];
    __shared__ int base[256];
    int t = threadIdx.x;
    for (int tile = blockIdx.x * T1; tile < e; tile += gridDim.x * T1) {
        int lim = min(e - tile, T1);
        hist[t] = 0;
        __syncthreads();
        for (int j = t; j < lim; j += 256)
            atomicAdd(&hist[dst[tile + j] >> BSH], 1);
        __syncthreads();
        int h = hist[t];
        int mybase = (h > 0) ? atomicAdd(&gcur[t], h) : 0;
        __syncthreads();
        hist[t] = 0;                 // reuse as local cursor
        base[t] = mybase;
        __syncthreads();
        for (int j = t; j < lim; j += 256) {
            int d = dst[tile + j], s = src[tile + j];
            int bk = d >> BSH;
            int loc = atomicAdd(&hist[bk], 1);
            bedges[base[bk] + loc] = ((unsigned)(d & (BSZ - 1)) << 17) | (unsigned)s;
        }
        __syncthreads();
    }
}

__global__ __launch_bounds__(256) void k_build(const unsigned* __restrict__ bedges,
        const int* __restrict__ boff, int* __restrict__ row_ptr,
        int* __restrict__ csr, float* __restrict__ dinv, int n) {
    __shared__ int hist[BSZ];
    __shared__ int cur[BSZ];
    __shared__ int sc[256];
    int b = blockIdx.x, t = threadIdx.x;
    int nodebase = b << BSH;
    int beg = boff[b], end = boff[b + 1];
    hist[t] = 0; hist[t + 256] = 0;
    __syncthreads();
    for (int j = beg + t; j < end; j += 256)
        atomicAdd(&hist[bedges[j] >> 17], 1);
    __syncthreads();
    int a0 = hist[2 * t], a1 = hist[2 * t + 1];
    int psum = a0 + a1;
    sc[t] = psum;
    __syncthreads();
    int acc = psum;
    for (int off = 1; off < 256; off <<= 1) {
        int x = (t >= off) ? sc[t - off] : 0;
        __syncthreads();
        acc += x;
        sc[t] = acc;
        __syncthreads();
    }
    int excl = acc - psum;           // exclusive over node pairs
    int e0 = beg + excl, e1 = beg + excl + a0;
    cur[2 * t] = e0;
    cur[2 * t + 1] = e1;
    int n0 = nodebase + 2 * t, n1 = nodebase + 2 * t + 1;
    if (n0 < n) { row_ptr[n0] = e0; dinv[n0] = rsqrtf((float)(a0 + 1)); }
    if (n1 < n) { row_ptr[n1] = e1; dinv[n1] = rsqrtf((float)(a1 + 1)); }
    __syncthreads();
    for (int j = beg + t; j < end; j += 256) {
        unsigned p = bedges[j];
        int pos = atomicAdd(&cur[p >> 17], 1);
        csr[pos] = (int)(p & 0x1FFFFu);
    }
}

// ---------- layer compute ----------
// A is stored as 4 planes of 16 channels; plane p row = 32B (16 halves).
// Aplane_p[n][cc] at A[p*(N<<4) + (n<<4) + cc]. A plane = 3.2MB -> L2-resident.

// A[n][c] = half( dinv[n] * sum_k x[n][k]*W0[k][c] )
__global__ __launch_bounds__(256) void k_lin0(const float* __restrict__ x,
        const float* __restrict__ W0, const float* __restrict__ dinv,
        __half* __restrict__ A, int n_nodes) {
    __shared__ float w[4 * HD];
    int t = threadIdx.x;
    w[t] = W0[t];
    __syncthreads();
    int n = blockIdx.x * 4 + (t >> 6);
    int c = t & 63;
    if (n >= n_nodes) return;
    float x0 = x[n * 4 + 0], x1 = x[n * 4 + 1], x2 = x[n * 4 + 2], x3 = x[n * 4 + 3];
    float v = x0 * w[c] + x1 * w[64 + c] + x2 * w[128 + c] + x3 * w[192 + c];
    size_t pbase = (size_t)(c >> 4) * ((size_t)n_nodes << 4);
    A[pbase + ((size_t)n << 4) + (c & 15)] = __float2half(v * dinv[n]);
}

// CSR gather-aggregate over ONE plane (32B rows, 32 edges/wave-instr, 2 nodes
// in flight per wave): B[n][c] = dinv[n]*(A[n][c] + sum_in A[src][c]) + bias[c]
__global__ __launch_bounds__(256) void k_aggr(const int* __restrict__ row_ptr,
        const int* __restrict__ csr, const __half* __restrict__ A,
        const float* __restrict__ dinv, const float* __restrict__ bias,
        float* __restrict__ B, float* __restrict__ stats, int n_nodes, int plane) {
    int t = threadIdx.x;
    int lane = t & 63, wv = t >> 6;
    int eg = lane >> 1, cg = lane & 1;     // edge slot 0..31, channel group 0..1
    const __half* Ap = A + (size_t)plane * ((size_t)n_nodes << 4);
    int cbase = (plane << 4) + (cg << 3);  // global channel base
    float st[8], st2[8];
    #pragma unroll
    for (int k = 0; k < 8; ++k) { st[k] = 0.f; st2[k] = 0.f; }
    for (int base = blockIdx.x * 8 + wv * 2; base < n_nodes; base += gridDim.x * 8) {
        int n0 = base, n1 = base + 1;
        bool has1 = (n1 < n_nodes);
        int r0 = __builtin_nontemporal_load(&row_ptr[n0]);
        int r1 = __builtin_nontemporal_load(&row_ptr[n0 + 1]);
        int r2 = has1 ? __builtin_nontemporal_load(&row_ptr[n0 + 2]) : r1;
        int beg0 = r0, end0 = r1, beg1 = r1, end1 = r2;
        float acc0[8], acc1[8];
        float msl = (eg == 0) ? 1.f : 0.f;
        {   // self-loop terms (kept only by eg==0 lanes)
            uint4 u0 = *reinterpret_cast<const uint4*>(Ap + ((size_t)n0 << 4) + (cg << 3));
            uint4 u1 = *reinterpret_cast<const uint4*>(Ap + ((size_t)(has1 ? n1 : n0) << 4) + (cg << 3));
            float f0[8], f1[8];
            h8_to_f(u0, f0); h8_to_f(u1, f1);
            float m1 = has1 ? msl : 0.f;
            #pragma unroll
            for (int k = 0; k < 8; ++k) { acc0[k] = msl * f0[k]; acc1[k] = m1 * f1[k]; }
        }
        int it0 = (end0 - beg0 + 31) >> 5;
        int it1 = (end1 - beg1 + 31) >> 5;
        int nit = it0 > it1 ? it0 : it1;
        for (int kk = 0; kk < nit; ++kk) {
            int i0 = beg0 + (kk << 5) + eg;
            int i1 = beg1 + (kk << 5) + eg;
            float m0 = (i0 < end0) ? 1.f : 0.f;
            float m1 = (i1 < end1) ? 1.f : 0.f;
            int i0c = (i0 < end0) ? i0 : 0;
            int i1c = (i1 < end1) ? i1 : 0;
            int s0 = __builtin_nontemporal_load(&csr[i0c]);
            int s1 = __builtin_nontemporal_load(&csr[i1c]);
            uint4 u0 = *reinterpret_cast<const uint4*>(Ap + ((size_t)s0 << 4) + (cg << 3));
            uint4 u1 = *reinterpret_cast<const uint4*>(Ap + ((size_t)s1 << 4) + (cg << 3));
            float f0[8], f1[8];
            h8_to_f(u0, f0); h8_to_f(u1, f1);
            #pragma unroll
            for (int k = 0; k < 8; ++k) {
                acc0[k] = fmaf(m0, f0[k], acc0[k]);
                acc1[k] = fmaf(m1, f1[k], acc1[k]);
            }
        }
        // reduce over edge slots: eg bits are lane bits 1..5
        #pragma unroll
        for (int d = 2; d < 64; d <<= 1) {
            #pragma unroll
            for (int k = 0; k < 8; ++k) {
                acc0[k] += __shfl_xor(acc0[k], d, 64);
                acc1[k] += __shfl_xor(acc1[k], d, 64);
            }
        }
        if (eg == 0) {
            float dv0 = dinv[n0];
            float v0[8];
            #pragma unroll
            for (int k = 0; k < 8; ++k) {
                v0[k] = dv0 * acc0[k] + bias[cbase + k];
                st[k] += v0[k]; st2[k] += v0[k] * v0[k];
            }
            vf4* bp0 = reinterpret_cast<vf4*>(B + ((size_t)n0 << 6) + cbase);
            vf4 w0a = { v0[0], v0[1], v0[2], v0[3] };
            vf4 w0b = { v0[4], v0[5], v0[6], v0[7] };
            __builtin_nontemporal_store(w0a, bp0);
            __builtin_nontemporal_store(w0b, bp0 + 1);
            if (has1) {
                float dv1 = dinv[n1];
                float v1[8];
                #pragma unroll
                for (int k = 0; k < 8; ++k) {
                    v1[k] = dv1 * acc1[k] + bias[cbase + k];
                    st[k] += v1[k]; st2[k] += v1[k] * v1[k];
                }
                vf4* bp1 = reinterpret_cast<vf4*>(B + ((size_t)n1 << 6) + cbase);
                vf4 w1a = { v1[0], v1[1], v1[2], v1[3] };
                vf4 w1b = { v1[4], v1[5], v1[6], v1[7] };
                __builtin_nontemporal_store(w1a, bp1);
                __builtin_nontemporal_store(w1b, bp1 + 1);
            }
        }
    }
    __shared__ float ls[4][16], ls2[4][16];
    if (eg == 0) {
        #pragma unroll
        for (int k = 0; k < 8; ++k) {
            ls[wv][(cg << 3) + k] = st[k];
            ls2[wv][(cg << 3) + k] = st2[k];
        }
    }
    __syncthreads();
    if (t < 16) {
        float a = ls[0][t] + ls[1][t] + ls[2][t] + ls[3][t];
        float a2 = ls2[0][t] + ls2[1][t] + ls2[2][t] + ls2[3][t];
        atomAddF(&stats[(plane << 4) + t], a);
        atomAddF(&stats[64 + (plane << 4) + t], a2);
    }
}

// A(half planes) <- dinv[n] * (relu(bn(B)) @ W1)   (BN0+ReLU fused into row staging)
__global__ __launch_bounds__(256) void k_lin1(const float* __restrict__ B,
        const float* __restrict__ W, const float* __restrict__ dinv,
        const float* __restrict__ stats, const float* __restrict__ g,
        const float* __restrict__ be, __half* __restrict__ A, int n_nodes) {
    __shared__ float w[HD * HD];
    __shared__ float rows[4][HD];
    int t = threadIdx.x;
    for (int i = t; i < HD * HD; i += 256) w[i] = W[i];
    int wv = t >> 6, c = t & 63;
    float inv_n = 1.0f / (float)n_nodes;
    float mu = stats[c] * inv_n;
    float var = stats[64 + c] * inv_n - mu * mu;
    float sc = g[c] * rsqrtf(var + EPS);
    float sh = be[c] - mu * sc;
    size_t pbase = (size_t)(c >> 4) * ((size_t)n_nodes << 4);
    int cc = c & 15;
    int ngroups = (n_nodes + 3) >> 2;
    for (int gidx = blockIdx.x; gidx < ngroups; gidx += gridDim.x) {
        __syncthreads();
        int n = gidx * 4 + wv;
        float rv = (n < n_nodes) ? fmaxf(sc * B[((size_t)n << 6) + c] + sh, 0.f) : 0.f;
        rows[wv][c] = rv;
        __syncthreads();
        if (n < n_nodes) {
            float acc = 0.f;
            #pragma unroll
            for (int k = 0; k < HD; k++) acc = fmaf(rows[wv][k], w[k * 64 + c], acc);
            A[pbase + ((size_t)n << 4) + cc] = __float2half(acc * dinv[n]);
        }
    }
}

// fused: h = relu(bn1(B)); out = sigmoid(relu(relu(h@Wm0+bm0)@Wm1+bm1)@Wm2+bm2)
__global__ __launch_bounds__(64) void k_mlp(const float* __restrict__ B,
        const float* __restrict__ stats, const float* __restrict__ g,
        const float* __restrict__ be,
        const float* __restrict__ Wm0, const float* __restrict__ bm0,
        const float* __restrict__ Wm1, const float* __restrict__ bm1,
        const float* __restrict__ Wm2, const float* __restrict__ bm2,
        float* __restrict__ out, int n_nodes) {
    __shared__ float rows[64][65];
    int t = threadIdx.x;
    float inv_n = 1.0f / (float)n_nodes;
    float mu = stats[t] * inv_n;
    float var = stats[64 + t] * inv_n - mu * mu;
    float sc = g[t] * rsqrtf(var + EPS);
    float sh = be[t] - mu * sc;
    int nbase = blockIdx.x * 64;
    #pragma unroll 4
    for (int r = 0; r < 64; r++) {
        int nn = nbase + r;
        rows[r][t] = (nn < n_nodes) ? fmaxf(sc * B[((size_t)nn << 6) + t] + sh, 0.f) : 0.f;
    }
    __syncthreads();
    int n = nbase + t;
    if (n >= n_nodes) return;

    float a1[64];
    #pragma unroll
    for (int cc = 0; cc < 4; ++cc) {
        float acc[16];
        #pragma unroll
        for (int j = 0; j < 16; ++j) acc[j] = bm0[cc * 16 + j];
        for (int k = 0; k < 64; ++k) {
            float hv = rows[t][k];
            #pragma unroll
            for (int j = 0; j < 16; ++j)
                acc[j] = fmaf(hv, Wm0[k * 64 + cc * 16 + j], acc[j]);
        }
        #pragma unroll
        for (int j = 0; j < 16; ++j) a1[cc * 16 + j] = fmaxf(acc[j], 0.f);
    }
    #pragma unroll
    for (int k = 0; k < 64; ++k) rows[t][k] = a1[k];

    float a2[32];
    #pragma unroll
    for (int cc = 0; cc < 2; ++cc) {
        float acc[16];
        #pragma unroll
        for (int j = 0; j < 16; ++j) acc[j] = bm1[cc * 16 + j];
        for (int k = 0; k < 64; ++k) {
            float hv = rows[t][k];
            #pragma unroll
            for (int j = 0; j < 16; ++j)
                acc[j] = fmaf(hv, Wm1[k * 32 + cc * 16 + j], acc[j]);
        }
        #pragma unroll
        for (int j = 0; j < 16; ++j) a2[cc * 16 + j] = fmaxf(acc[j], 0.f);
    }
    float z = bm2[0];
    #pragma unroll
    for (int k = 0; k < 32; ++k) z = fmaf(a2[k], Wm2[k], z);
    out[n] = 1.0f / (1.0f + __expf(-z));
}

extern "C" void kernel_launch(void* const* d_in, const int* in_sizes, int n_in,
                              void* d_out, int out_size, void* d_ws, size_t ws_size,
                              hipStream_t stream) {
    const float* x   = (const float*)d_in[0];
    const int*   src = (const int*)d_in[1];
    const int*   dst = (const int*)d_in[2];
    const float* W0  = (const float*)d_in[3];
    const float* b0  = (const float*)d_in[4];
    const float* W1  = (const float*)d_in[5];
    const float* b1  = (const float*)d_in[6];
    const float* g0  = (const float*)d_in[7];
    const float* be0 = (const float*)d_in[8];
    const float* g1  = (const float*)d_in[9];
    const float* be1 = (const float*)d_in[10];
    const float* Wm0 = (const float*)d_in[11];
    const float* bm0 = (const float*)d_in[12];
    const float* Wm1 = (const float*)d_in[13];
    const float* bm1 = (const float*)d_in[14];
    const float* Wm2 = (const float*)d_in[15];
    const float* bm2 = (const float*)d_in[16];

    int n = in_sizes[0] / 4;
    int e = in_sizes[1];
    float* out = (float*)d_out;

    char* ws = (char*)d_ws;
    auto alignup = [](size_t v) { return (v + 255) & ~(size_t)255; };
    size_t o = 0;
    int*      bcnt    = (int*)(ws + o);      o += alignup(256 * 4);
    int*      boff    = (int*)(ws + o);      o += alignup(257 * 4);
    int*      gcur    = (int*)(ws + o);      o += alignup(256 * 4);
    float*    stats   = (float*)(ws + o);    o += alignup(256 * 4);
    int*      row_ptr = (int*)(ws + o);      o += alignup((size_t)(n + 1) * 4);
    float*    dinv    = (float*)(ws + o);    o += alignup((size_t)n * 4);
    unsigned* bedges  = (unsigned*)(ws + o); o += alignup((size_t)e * 4);
    int*      csr     = (int*)(ws + o);      o += alignup((size_t)e * 4);
    __half*   A       = (__half*)(ws + o);   o += alignup((size_t)n * 64 * 2);
    float*    B       = (float*)(ws + o);

    int nb     = (n + BSZ - 1) >> BSH;        // 196 buckets for n=100k (requires n<=131072)
    int gN4    = (n + 3) / 4;
    int ntiles = (e + T1 - 1) / T1;
    int gMLP   = (n + 63) / 64;
    int gAGG   = 2048;

    (void)hipMemsetAsync(bcnt, 0, 256 * 4, stream);
    (void)hipMemsetAsync(stats, 0, 256 * 4, stream);

    // ---- CSR build (bucketed, once, reused by both layers) ----
    k_bhist<<<512, 256, 0, stream>>>(dst, bcnt, e);
    k_bscan<<<1, 256, 0, stream>>>(bcnt, boff, gcur, row_ptr, nb, n, e);
    k_bucket<<<ntiles, 256, 0, stream>>>(src, dst, gcur, bedges, e);
    k_build<<<nb, 256, 0, stream>>>(bedges, boff, row_ptr, csr, dinv, n);

    // ---- layer 1 ----
    k_lin0<<<gN4, 256, 0, stream>>>(x, W0, dinv, A, n);
    for (int p = 0; p < 4; ++p)
        k_aggr<<<gAGG, 256, 0, stream>>>(row_ptr, csr, A, dinv, b0, B, stats, n, p);

    // ---- layer 2 (BN0+ReLU fused into lin1) ----
    k_lin1<<<2048, 256, 0, stream>>>(B, W1, dinv, stats, g0, be0, A, n);
    for (int p = 0; p < 4; ++p)
        k_aggr<<<gAGG, 256, 0, stream>>>(row_ptr, csr, A, dinv, b1, B, stats + 128, n, p);

    // ---- MLP head (BN1+ReLU fused) ----
    k_mlp<<<gMLP, 64, 0, stream>>>(B, stats + 128, g1, be1,
                                   Wm0, bm0, Wm1, bm1, Wm2, bm2, out, n);
}

// Round 8
// 418.113 us; speedup vs baseline: 1.8131x; 1.8131x over previous
//
#include <hip/hip_runtime.h>
#include <hip/hip_fp16.h>
#include <math.h>

#define HD 64
#define EPS 1e-5f
#define BSH 9                   // bucket shift: 512 nodes per bucket
#define BSZ 512
#define T1 16384                // edges per tile in k_bucket
// packing: n <= 131072 (2^17) required: packed = (local_dst<<17) | src

__device__ __forceinline__ float atomAddF(float* p, float v) {
    return unsafeAtomicAdd(p, v);   // native global_atomic_add_f32 on gfx950
}

// ---------- CSR build (bucketed counting sort) ----------

__global__ __launch_bounds__(256) void k_bhist(const int* __restrict__ dst,
        int* __restrict__ bcnt, int e) {
    __shared__ int h[256];
    int t = threadIdx.x;
    h[t] = 0;
    __syncthreads();
    for (int i = blockIdx.x * 256 + t; i < e; i += gridDim.x * 256)
        atomicAdd(&h[dst[i] >> BSH], 1);
    __syncthreads();
    if (h[t]) atomicAdd(&bcnt[t], h[t]);
}

__global__ __launch_bounds__(256) void k_bscan(const int* __restrict__ bcnt,
        int* __restrict__ boff, int* __restrict__ gcur,
        int* __restrict__ row_ptr, int nb, int n, int e) {
    __shared__ int sc[256];
    int t = threadIdx.x;
    int v = (t < nb) ? bcnt[t] : 0;
    sc[t] = v;
    __syncthreads();
    int acc = v;
    for (int off = 1; off < 256; off <<= 1) {
        int x = (t >= off) ? sc[t - off] : 0;
        __syncthreads();
        acc += x;
        sc[t] = acc;
        __syncthreads();
    }
    int ex = acc - v;
    boff[t] = ex;                    // thread nb writes boff[nb] = e
    gcur[t] = ex;
    if (t == 0) row_ptr[n] = e;
}

__global__ __launch_bounds__(256) void k_bucket(const int* __restrict__ src,
        const int* __restrict__ dst, int* __restrict__ gcur,
        unsigned* __restrict__ bedges, int e) {
    __shared__ int hist[256];
    __shared__ int base[256];
    int t = threadIdx.x;
    for (int tile = blockIdx.x * T1; tile < e; tile += gridDim.x * T1) {
        int lim = min(e - tile, T1);
        hist[t] = 0;
        __syncthreads();
        for (int j = t; j < lim; j += 256)
            atomicAdd(&hist[dst[tile + j] >> BSH], 1);
        __syncthreads();
        int h = hist[t];
        int mybase = (h > 0) ? atomicAdd(&gcur[t], h) : 0;
        __syncthreads();
        hist[t] = 0;                 // reuse as local cursor
        base[t] = mybase;
        __syncthreads();
        for (int j = t; j < lim; j += 256) {
            int d = dst[tile + j], s = src[tile + j];
            int bk = d >> BSH;
            int loc = atomicAdd(&hist[bk], 1);
            bedges[base[bk] + loc] = ((unsigned)(d & (BSZ - 1)) << 17) | (unsigned)s;
        }
        __syncthreads();
    }
}

// pass 2: one block per bucket -> row_ptr, dinv, csr sorted by dst.
// csr keeps the PACKED word: (local512_dst<<17)|src  (aggr needs both fields)
__global__ __launch_bounds__(256) void k_build(const unsigned* __restrict__ bedges,
        const int* __restrict__ boff, int* __restrict__ row_ptr,
        unsigned* __restrict__ csr, float* __restrict__ dinv, int n) {
    __shared__ int hist[BSZ];
    __shared__ int cur[BSZ];
    __shared__ int sc[256];
    int b = blockIdx.x, t = threadIdx.x;
    int nodebase = b << BSH;
    int beg = boff[b], end = boff[b + 1];
    hist[t] = 0; hist[t + 256] = 0;
    __syncthreads();
    for (int j = beg + t; j < end; j += 256)
        atomicAdd(&hist[bedges[j] >> 17], 1);
    __syncthreads();
    int a0 = hist[2 * t], a1 = hist[2 * t + 1];
    int psum = a0 + a1;
    sc[t] = psum;
    __syncthreads();
    int acc = psum;
    for (int off = 1; off < 256; off <<= 1) {
        int x = (t >= off) ? sc[t - off] : 0;
        __syncthreads();
        acc += x;
        sc[t] = acc;
        __syncthreads();
    }
    int excl = acc - psum;           // exclusive over node pairs
    int e0 = beg + excl, e1 = beg + excl + a0;
    cur[2 * t] = e0;
    cur[2 * t + 1] = e1;
    int n0 = nodebase + 2 * t, n1 = nodebase + 2 * t + 1;
    if (n0 < n) { row_ptr[n0] = e0; dinv[n0] = rsqrtf((float)(a0 + 1)); }
    if (n1 < n) { row_ptr[n1] = e1; dinv[n1] = rsqrtf((float)(a1 + 1)); }
    __syncthreads();
    for (int j = beg + t; j < end; j += 256) {
        unsigned p = bedges[j];
        int pos = atomicAdd(&cur[p >> 17], 1);
        csr[pos] = p;
    }
}

// ---------- layer compute ----------
// A: fp16, linear rows A[n*64+c] (128B per row)

// A[n][c] = half( dinv[n] * sum_k x[n][k]*W0[k][c] )
__global__ __launch_bounds__(256) void k_lin0(const float* __restrict__ x,
        const float* __restrict__ W0, const float* __restrict__ dinv,
        __half* __restrict__ A, int n_nodes) {
    __shared__ float w[4 * HD];
    int t = threadIdx.x;
    w[t] = W0[t];
    __syncthreads();
    int n = blockIdx.x * 4 + (t >> 6);
    int c = t & 63;
    if (n >= n_nodes) return;
    float x0 = x[n * 4 + 0], x1 = x[n * 4 + 1], x2 = x[n * 4 + 2], x3 = x[n * 4 + 3];
    float v = x0 * w[c] + x1 * w[64 + c] + x2 * w[128 + c] + x3 * w[192 + c];
    A[((size_t)n << 6) + c] = __float2half(v * dinv[n]);
}

// edge-parallel aggregation: one block per 64-node group, fp32 LDS accumulator.
// Each half-wave owns a contiguous dst-sorted edge stream; 32 lanes read the
// full 128B fp16 row of A[src]; register-accumulate runs of equal dst, flush
// to LDS on change. Finalize (self-loop+dinv+bias+stats) fused after barrier.
__global__ __launch_bounds__(256) void k_aggr(const int* __restrict__ row_ptr,
        const unsigned* __restrict__ pedges, const __half* __restrict__ A,
        const float* __restrict__ dinv, const float* __restrict__ bias,
        float* __restrict__ B, float* __restrict__ stats, int n_nodes) {
    __shared__ float acc[64 * 65];
    __shared__ float ls[4][64], ls2[4][64];
    int t = threadIdx.x;
    for (int i = t; i < 64 * 65; i += 256) acc[i] = 0.f;
    int nodebase = blockIdx.x << 6;
    int nend = min(nodebase + 64, n_nodes);
    int ebeg = row_ptr[nodebase];
    int eend = row_ptr[nend];
    int nedges = eend - ebeg;
    __syncthreads();

    int wv = t >> 6, lane = t & 63;
    int half = lane >> 5, l = lane & 31;
    int s = wv * 2 + half;                     // stream 0..7
    int sbeg = ebeg + (int)(((long long)nedges * s) >> 3);
    int send = ebeg + (int)(((long long)nedges * (s + 1)) >> 3);
    const unsigned* A32 = (const unsigned*)A;  // 2 halves per word; row = 32 words
    int l2 = l << 1;

    float ax = 0.f, ay = 0.f;
    int cur = -1;
    int j = sbeg;
    #define PROC(P, U) {                                                       \
        int d_ = (int)((P) >> 17) & 63;                                        \
        float2 f_ = __half22float2(*(const __half2*)&(U));                     \
        if (d_ != cur) {                                                       \
            if (cur >= 0) {                                                    \
                atomicAdd(&acc[cur * 65 + l2], ax);                            \
                atomicAdd(&acc[cur * 65 + l2 + 1], ay);                        \
            }                                                                  \
            ax = 0.f; ay = 0.f; cur = d_;                                      \
        }                                                                      \
        ax += f_.x; ay += f_.y; }

    for (; j + 4 <= send; j += 4) {
        unsigned p0 = pedges[j], p1 = pedges[j + 1];
        unsigned p2 = pedges[j + 2], p3 = pedges[j + 3];
        unsigned u0 = A32[((p0 & 0x1FFFFu) << 5) + l];
        unsigned u1 = A32[((p1 & 0x1FFFFu) << 5) + l];
        unsigned u2 = A32[((p2 & 0x1FFFFu) << 5) + l];
        unsigned u3 = A32[((p3 & 0x1FFFFu) << 5) + l];
        PROC(p0, u0); PROC(p1, u1); PROC(p2, u2); PROC(p3, u3);
    }
    for (; j < send; ++j) {
        unsigned p0 = pedges[j];
        unsigned u0 = A32[((p0 & 0x1FFFFu) << 5) + l];
        PROC(p0, u0);
    }
    if (cur >= 0) {
        atomicAdd(&acc[cur * 65 + l2], ax);
        atomicAdd(&acc[cur * 65 + l2 + 1], ay);
    }
    #undef PROC
    __syncthreads();

    // finalize: wave wv handles rows wv, wv+4, ... ; lane = channel
    int c = lane;
    float st = 0.f, st2 = 0.f;
    for (int r = wv; r < 64; r += 4) {
        int node = nodebase + r;
        if (node < n_nodes) {
            float v = acc[r * 65 + c] + __half2float(A[((size_t)node << 6) + c]);
            v = dinv[node] * v + bias[c];
            B[((size_t)node << 6) + c] = v;
            st += v; st2 += v * v;
        }
    }
    ls[wv][c] = st; ls2[wv][c] = st2;
    __syncthreads();
    if (t < 64) {
        atomAddF(&stats[t], ls[0][t] + ls[1][t] + ls[2][t] + ls[3][t]);
        atomAddF(&stats[64 + t], ls2[0][t] + ls2[1][t] + ls2[2][t] + ls2[3][t]);
    }
}

// A(half) <- dinv[n] * (relu(bn(B)) @ W1)   (BN0+ReLU fused into row staging)
__global__ __launch_bounds__(256) void k_lin1(const float* __restrict__ B,
        const float* __restrict__ W, const float* __restrict__ dinv,
        const float* __restrict__ stats, const float* __restrict__ g,
        const float* __restrict__ be, __half* __restrict__ A, int n_nodes) {
    __shared__ float w[HD * HD];
    __shared__ float rows[4][HD];
    int t = threadIdx.x;
    for (int i = t; i < HD * HD; i += 256) w[i] = W[i];
    int wv = t >> 6, c = t & 63;
    float inv_n = 1.0f / (float)n_nodes;
    float mu = stats[c] * inv_n;
    float var = stats[64 + c] * inv_n - mu * mu;
    float sc = g[c] * rsqrtf(var + EPS);
    float sh = be[c] - mu * sc;
    int ngroups = (n_nodes + 3) >> 2;
    for (int gidx = blockIdx.x; gidx < ngroups; gidx += gridDim.x) {
        __syncthreads();
        int n = gidx * 4 + wv;
        float rv = (n < n_nodes) ? fmaxf(sc * B[((size_t)n << 6) + c] + sh, 0.f) : 0.f;
        rows[wv][c] = rv;
        __syncthreads();
        if (n < n_nodes) {
            float acc = 0.f;
            #pragma unroll
            for (int k = 0; k < HD; k++) acc = fmaf(rows[wv][k], w[k * 64 + c], acc);
            A[((size_t)n << 6) + c] = __float2half(acc * dinv[n]);
        }
    }
}

// fused: h = relu(bn1(B)); out = sigmoid(relu(relu(h@Wm0+bm0)@Wm1+bm1)@Wm2+bm2)
__global__ __launch_bounds__(64) void k_mlp(const float* __restrict__ B,
        const float* __restrict__ stats, const float* __restrict__ g,
        const float* __restrict__ be,
        const float* __restrict__ Wm0, const float* __restrict__ bm0,
        const float* __restrict__ Wm1, const float* __restrict__ bm1,
        const float* __restrict__ Wm2, const float* __restrict__ bm2,
        float* __restrict__ out, int n_nodes) {
    __shared__ float rows[64][65];
    int t = threadIdx.x;
    float inv_n = 1.0f / (float)n_nodes;
    float mu = stats[t] * inv_n;
    float var = stats[64 + t] * inv_n - mu * mu;
    float sc = g[t] * rsqrtf(var + EPS);
    float sh = be[t] - mu * sc;
    int nbase = blockIdx.x * 64;
    #pragma unroll 4
    for (int r = 0; r < 64; r++) {
        int nn = nbase + r;
        rows[r][t] = (nn < n_nodes) ? fmaxf(sc * B[((size_t)nn << 6) + t] + sh, 0.f) : 0.f;
    }
    __syncthreads();
    int n = nbase + t;
    if (n >= n_nodes) return;

    float a1[64];
    #pragma unroll
    for (int cc = 0; cc < 4; ++cc) {
        float acc[16];
        #pragma unroll
        for (int j = 0; j < 16; ++j) acc[j] = bm0[cc * 16 + j];
        for (int k = 0; k < 64; ++k) {
            float hv = rows[t][k];
            #pragma unroll
            for (int j = 0; j < 16; ++j)
                acc[j] = fmaf(hv, Wm0[k * 64 + cc * 16 + j], acc[j]);
        }
        #pragma unroll
        for (int j = 0; j < 16; ++j) a1[cc * 16 + j] = fmaxf(acc[j], 0.f);
    }
    #pragma unroll
    for (int k = 0; k < 64; ++k) rows[t][k] = a1[k];

    float a2[32];
    #pragma unroll
    for (int cc = 0; cc < 2; ++cc) {
        float acc[16];
        #pragma unroll
        for (int j = 0; j < 16; ++j) acc[j] = bm1[cc * 16 + j];
        for (int k = 0; k < 64; ++k) {
            float hv = rows[t][k];
            #pragma unroll
            for (int j = 0; j < 16; ++j)
                acc[j] = fmaf(hv, Wm1[k * 32 + cc * 16 + j], acc[j]);
        }
        #pragma unroll
        for (int j = 0; j < 16; ++j) a2[cc * 16 + j] = fmaxf(acc[j], 0.f);
    }
    float z = bm2[0];
    #pragma unroll
    for (int k = 0; k < 32; ++k) z = fmaf(a2[k], Wm2[k], z);
    out[n] = 1.0f / (1.0f + __expf(-z));
}

extern "C" void kernel_launch(void* const* d_in, const int* in_sizes, int n_in,
                              void* d_out, int out_size, void* d_ws, size_t ws_size,
                              hipStream_t stream) {
    const float* x   = (const float*)d_in[0];
    const int*   src = (const int*)d_in[1];
    const int*   dst = (const int*)d_in[2];
    const float* W0  = (const float*)d_in[3];
    const float* b0  = (const float*)d_in[4];
    const float* W1  = (const float*)d_in[5];
    const float* b1  = (const float*)d_in[6];
    const float* g0  = (const float*)d_in[7];
    const float* be0 = (const float*)d_in[8];
    const float* g1  = (const float*)d_in[9];
    const float* be1 = (const float*)d_in[10];
    const float* Wm0 = (const float*)d_in[11];
    const float* bm0 = (const float*)d_in[12];
    const float* Wm1 = (const float*)d_in[13];
    const float* bm1 = (const float*)d_in[14];
    const float* Wm2 = (const float*)d_in[15];
    const float* bm2 = (const float*)d_in[16];

    int n = in_sizes[0] / 4;
    int e = in_sizes[1];
    float* out = (float*)d_out;

    char* ws = (char*)d_ws;
    auto alignup = [](size_t v) { return (v + 255) & ~(size_t)255; };
    size_t o = 0;
    int*      bcnt    = (int*)(ws + o);      o += alignup(256 * 4);
    int*      boff    = (int*)(ws + o);      o += alignup(257 * 4);
    int*      gcur    = (int*)(ws + o);      o += alignup(256 * 4);
    float*    stats   = (float*)(ws + o);    o += alignup(256 * 4);
    int*      row_ptr = (int*)(ws + o);      o += alignup((size_t)(n + 1) * 4);
    float*    dinv    = (float*)(ws + o);    o += alignup((size_t)n * 4);
    unsigned* bedges  = (unsigned*)(ws + o); o += alignup((size_t)e * 4);
    unsigned* csr     = (unsigned*)(ws + o); o += alignup((size_t)e * 4);
    __half*   A       = (__half*)(ws + o);   o += alignup((size_t)n * 64 * 2);
    float*    B       = (float*)(ws + o);

    int nb     = (n + BSZ - 1) >> BSH;        // 196 buckets for n=100k (requires n<=131072)
    int gN4    = (n + 3) / 4;
    int ntiles = (e + T1 - 1) / T1;
    int gMLP   = (n + 63) / 64;
    int gAGG   = (n + 63) / 64;               // one block per 64-node group

    (void)hipMemsetAsync(bcnt, 0, 256 * 4, stream);
    (void)hipMemsetAsync(stats, 0, 256 * 4, stream);

    // ---- CSR build (bucketed, once, reused by both layers) ----
    k_bhist<<<512, 256, 0, stream>>>(dst, bcnt, e);
    k_bscan<<<1, 256, 0, stream>>>(bcnt, boff, gcur, row_ptr, nb, n, e);
    k_bucket<<<ntiles, 256, 0, stream>>>(src, dst, gcur, bedges, e);
    k_build<<<nb, 256, 0, stream>>>(bedges, boff, row_ptr, csr, dinv, n);

    // ---- layer 1 ----
    k_lin0<<<gN4, 256, 0, stream>>>(x, W0, dinv, A, n);
    k_aggr<<<gAGG, 256, 0, stream>>>(row_ptr, csr, A, dinv, b0, B, stats, n);

    // ---- layer 2 (BN0+ReLU fused into lin1) ----
    k_lin1<<<2048, 256, 0, stream>>>(B, W1, dinv, stats, g0, be0, A, n);
    k_aggr<<<gAGG, 256, 0, stream>>>(row_ptr, csr, A, dinv, b1, B, stats + 128, n);

    // ---- MLP head (BN1+ReLU fused) ----
    k_mlp<<<gMLP, 64, 0, stream>>>(B, stats + 128, g1, be1,
                                   Wm0, bm0, Wm1, bm1, Wm2, bm2, out, n);
}

// Round 9
// 401.135 us; speedup vs baseline: 1.8898x; 1.0423x over previous
//
#include <hip/hip_runtime.h>
#include <hip/hip_fp16.h>
#include <math.h>

#define HD 64
#define EPS 1e-5f
#define BSH 9                   // bucket shift: 512 nodes per bucket
#define BSZ 512
#define T1 16384                // edges per tile in k_bucket
// packing: n <= 131072 (2^17) required: packed = (local_dst<<17) | src

__device__ __forceinline__ float atomAddF(float* p, float v) {
    return unsafeAtomicAdd(p, v);   // native global_atomic_add_f32 on gfx950
}

// ---------- CSR build (bucketed counting sort) ----------

__global__ __launch_bounds__(256) void k_bhist(const int* __restrict__ dst,
        int* __restrict__ bcnt, int e) {
    __shared__ int h[256];
    int t = threadIdx.x;
    h[t] = 0;
    __syncthreads();
    for (int i = blockIdx.x * 256 + t; i < e; i += gridDim.x * 256)
        atomicAdd(&h[dst[i] >> BSH], 1);
    __syncthreads();
    if (h[t]) atomicAdd(&bcnt[t], h[t]);
}

__global__ __launch_bounds__(256) void k_bscan(const int* __restrict__ bcnt,
        int* __restrict__ boff, int* __restrict__ gcur,
        int* __restrict__ row_ptr, int nb, int n, int e) {
    __shared__ int sc[256];
    int t = threadIdx.x;
    int v = (t < nb) ? bcnt[t] : 0;
    sc[t] = v;
    __syncthreads();
    int acc = v;
    for (int off = 1; off < 256; off <<= 1) {
        int x = (t >= off) ? sc[t - off] : 0;
        __syncthreads();
        acc += x;
        sc[t] = acc;
        __syncthreads();
    }
    int ex = acc - v;
    boff[t] = ex;                    // thread nb writes boff[nb] = e
    gcur[t] = ex;
    if (t == 0) row_ptr[n] = e;
}

__global__ __launch_bounds__(256) void k_bucket(const int* __restrict__ src,
        const int* __restrict__ dst, int* __restrict__ gcur,
        unsigned* __restrict__ bedges, int e) {
    __shared__ int hist[256];
    __shared__ int base[256];
    int t = threadIdx.x;
    for (int tile = blockIdx.x * T1; tile < e; tile += gridDim.x * T1) {
        int lim = min(e - tile, T1);
        hist[t] = 0;
        __syncthreads();
        for (int j = t; j < lim; j += 256)
            atomicAdd(&hist[dst[tile + j] >> BSH], 1);
        __syncthreads();
        int h = hist[t];
        int mybase = (h > 0) ? atomicAdd(&gcur[t], h) : 0;
        __syncthreads();
        hist[t] = 0;                 // reuse as local cursor
        base[t] = mybase;
        __syncthreads();
        for (int j = t; j < lim; j += 256) {
            int d = dst[tile + j], s = src[tile + j];
            int bk = d >> BSH;
            int loc = atomicAdd(&hist[bk], 1);
            bedges[base[bk] + loc] = ((unsigned)(d & (BSZ - 1)) << 17) | (unsigned)s;
        }
        __syncthreads();
    }
}

// pass 2: one block per bucket -> row_ptr, dinv, csr sorted by dst.
// csr keeps the PACKED word: (local512_dst<<17)|src  (aggr needs both fields)
__global__ __launch_bounds__(256) void k_build(const unsigned* __restrict__ bedges,
        const int* __restrict__ boff, int* __restrict__ row_ptr,
        unsigned* __restrict__ csr, float* __restrict__ dinv, int n) {
    __shared__ int hist[BSZ];
    __shared__ int cur[BSZ];
    __shared__ int sc[256];
    int b = blockIdx.x, t = threadIdx.x;
    int nodebase = b << BSH;
    int beg = boff[b], end = boff[b + 1];
    hist[t] = 0; hist[t + 256] = 0;
    __syncthreads();
    for (int j = beg + t; j < end; j += 256)
        atomicAdd(&hist[bedges[j] >> 17], 1);
    __syncthreads();
    int a0 = hist[2 * t], a1 = hist[2 * t + 1];
    int psum = a0 + a1;
    sc[t] = psum;
    __syncthreads();
    int acc = psum;
    for (int off = 1; off < 256; off <<= 1) {
        int x = (t >= off) ? sc[t - off] : 0;
        __syncthreads();
        acc += x;
        sc[t] = acc;
        __syncthreads();
    }
    int excl = acc - psum;           // exclusive over node pairs
    int e0 = beg + excl, e1 = beg + excl + a0;
    cur[2 * t] = e0;
    cur[2 * t + 1] = e1;
    int n0 = nodebase + 2 * t, n1 = nodebase + 2 * t + 1;
    if (n0 < n) { row_ptr[n0] = e0; dinv[n0] = rsqrtf((float)(a0 + 1)); }
    if (n1 < n) { row_ptr[n1] = e1; dinv[n1] = rsqrtf((float)(a1 + 1)); }
    __syncthreads();
    for (int j = beg + t; j < end; j += 256) {
        unsigned p = bedges[j];
        int pos = atomicAdd(&cur[p >> 17], 1);
        csr[pos] = p;
    }
}

// ---------- layer compute ----------
// A: fp16, linear rows A[n*64+c] (128B per row)

// A[n][c] = half( dinv[n] * sum_k x[n][k]*W0[k][c] )
__global__ __launch_bounds__(256) void k_lin0(const float* __restrict__ x,
        const float* __restrict__ W0, const float* __restrict__ dinv,
        __half* __restrict__ A, int n_nodes) {
    __shared__ float w[4 * HD];
    int t = threadIdx.x;
    w[t] = W0[t];
    __syncthreads();
    int n = blockIdx.x * 4 + (t >> 6);
    int c = t & 63;
    if (n >= n_nodes) return;
    float x0 = x[n * 4 + 0], x1 = x[n * 4 + 1], x2 = x[n * 4 + 2], x3 = x[n * 4 + 3];
    float v = x0 * w[c] + x1 * w[64 + c] + x2 * w[128 + c] + x3 * w[192 + c];
    A[((size_t)n << 6) + c] = __float2half(v * dinv[n]);
}

// edge-parallel aggregation: one block per 64-node group, fp32 LDS accumulator.
// 16-lane groups: each lane loads 8B (4 halves) of the 128B row -> one wave
// instruction covers 4 edges; 8-deep unroll -> 8 gathers in flight per group.
// Register-accumulate runs of equal dst (sorted), flush 4 LDS atomics on change.
__global__ __launch_bounds__(256) void k_aggr(const int* __restrict__ row_ptr,
        const unsigned* __restrict__ pedges, const __half* __restrict__ A,
        const float* __restrict__ dinv, const float* __restrict__ bias,
        float* __restrict__ B, float* __restrict__ stats, int n_nodes) {
    __shared__ float acc[64 * 65];
    __shared__ float ls[4][64], ls2[4][64];
    int t = threadIdx.x;
    for (int i = t; i < 64 * 65; i += 256) acc[i] = 0.f;
    int nodebase = blockIdx.x << 6;
    int nend = min(nodebase + 64, n_nodes);
    int ebeg = row_ptr[nodebase];
    int eend = row_ptr[nend];
    int nedges = eend - ebeg;
    __syncthreads();

    int wv = t >> 6, lane = t & 63;
    int sub = lane >> 4, ch = lane & 15;       // 16-lane group; ch*4 = channel base
    int s = wv * 4 + sub;                      // stream 0..15
    int sbeg = ebeg + (int)(((long long)nedges * s) >> 4);
    int send = ebeg + (int)(((long long)nedges * (s + 1)) >> 4);
    const uint2* A2 = (const uint2*)A;         // 16 uint2 per 64-half row

    float a0 = 0.f, a1 = 0.f, a2 = 0.f, a3 = 0.f;
    int cur = -1;

    #define FLUSH() if (cur >= 0) {                                            \
        int o_ = cur * 65 + (ch << 2);                                         \
        atomicAdd(&acc[o_ + 0], a0); atomicAdd(&acc[o_ + 1], a1);              \
        atomicAdd(&acc[o_ + 2], a2); atomicAdd(&acc[o_ + 3], a3); }

    #define PROC(P, U) {                                                       \
        int d_ = (int)((P) >> 17) & 63;                                        \
        if (d_ != cur) { FLUSH(); a0 = a1 = a2 = a3 = 0.f; cur = d_; }         \
        float2 f01_ = __half22float2(*(const __half2*)&(U).x);                 \
        float2 f23_ = __half22float2(*(const __half2*)&(U).y);                 \
        a0 += f01_.x; a1 += f01_.y; a2 += f23_.x; a3 += f23_.y; }

    int j = sbeg;
    for (; j + 8 <= send; j += 8) {
        unsigned p[8];
        uint2 u[8];
        #pragma unroll
        for (int k = 0; k < 8; ++k) p[k] = pedges[j + k];
        #pragma unroll
        for (int k = 0; k < 8; ++k)
            u[k] = A2[(((size_t)(p[k] & 0x1FFFFu)) << 4) + ch];
        #pragma unroll
        for (int k = 0; k < 8; ++k) PROC(p[k], u[k]);
    }
    for (; j < send; ++j) {
        unsigned p0 = pedges[j];
        uint2 u0 = A2[(((size_t)(p0 & 0x1FFFFu)) << 4) + ch];
        PROC(p0, u0);
    }
    FLUSH();
    #undef PROC
    #undef FLUSH
    __syncthreads();

    // finalize: wave wv handles rows wv, wv+4, ... ; lane = channel
    int c = lane;
    float st = 0.f, st2 = 0.f;
    for (int r = wv; r < 64; r += 4) {
        int node = nodebase + r;
        if (node < n_nodes) {
            float v = acc[r * 65 + c] + __half2float(A[((size_t)node << 6) + c]);
            v = dinv[node] * v + bias[c];
            B[((size_t)node << 6) + c] = v;
            st += v; st2 += v * v;
        }
    }
    ls[wv][c] = st; ls2[wv][c] = st2;
    __syncthreads();
    if (t < 64) {
        atomAddF(&stats[t], ls[0][t] + ls[1][t] + ls[2][t] + ls[3][t]);
        atomAddF(&stats[64 + t], ls2[0][t] + ls2[1][t] + ls2[2][t] + ls2[3][t]);
    }
}

// A(half) <- dinv[n] * (relu(bn(B)) @ W1)   (BN0+ReLU fused into row staging)
__global__ __launch_bounds__(256) void k_lin1(const float* __restrict__ B,
        const float* __restrict__ W, const float* __restrict__ dinv,
        const float* __restrict__ stats, const float* __restrict__ g,
        const float* __restrict__ be, __half* __restrict__ A, int n_nodes) {
    __shared__ float w[HD * HD];
    __shared__ float rows[4][HD];
    int t = threadIdx.x;
    for (int i = t; i < HD * HD; i += 256) w[i] = W[i];
    int wv = t >> 6, c = t & 63;
    float inv_n = 1.0f / (float)n_nodes;
    float mu = stats[c] * inv_n;
    float var = stats[64 + c] * inv_n - mu * mu;
    float sc = g[c] * rsqrtf(var + EPS);
    float sh = be[c] - mu * sc;
    int ngroups = (n_nodes + 3) >> 2;
    for (int gidx = blockIdx.x; gidx < ngroups; gidx += gridDim.x) {
        __syncthreads();
        int n = gidx * 4 + wv;
        float rv = (n < n_nodes) ? fmaxf(sc * B[((size_t)n << 6) + c] + sh, 0.f) : 0.f;
        rows[wv][c] = rv;
        __syncthreads();
        if (n < n_nodes) {
            float acc = 0.f;
            #pragma unroll
            for (int k = 0; k < HD; k++) acc = fmaf(rows[wv][k], w[k * 64 + c], acc);
            A[((size_t)n << 6) + c] = __float2half(acc * dinv[n]);
        }
    }
}

// fused: h = relu(bn1(B)); out = sigmoid(relu(relu(h@Wm0+bm0)@Wm1+bm1)@Wm2+bm2)
__global__ __launch_bounds__(64) void k_mlp(const float* __restrict__ B,
        const float* __restrict__ stats, const float* __restrict__ g,
        const float* __restrict__ be,
        const float* __restrict__ Wm0, const float* __restrict__ bm0,
        const float* __restrict__ Wm1, const float* __restrict__ bm1,
        const float* __restrict__ Wm2, const float* __restrict__ bm2,
        float* __restrict__ out, int n_nodes) {
    __shared__ float rows[64][65];
    int t = threadIdx.x;
    float inv_n = 1.0f / (float)n_nodes;
    float mu = stats[t] * inv_n;
    float var = stats[64 + t] * inv_n - mu * mu;
    float sc = g[t] * rsqrtf(var + EPS);
    float sh = be[t] - mu * sc;
    int nbase = blockIdx.x * 64;
    #pragma unroll 4
    for (int r = 0; r < 64; r++) {
        int nn = nbase + r;
        rows[r][t] = (nn < n_nodes) ? fmaxf(sc * B[((size_t)nn << 6) + t] + sh, 0.f) : 0.f;
    }
    __syncthreads();
    int n = nbase + t;
    if (n >= n_nodes) return;

    float a1[64];
    #pragma unroll
    for (int cc = 0; cc < 4; ++cc) {
        float acc[16];
        #pragma unroll
        for (int j = 0; j < 16; ++j) acc[j] = bm0[cc * 16 + j];
        for (int k = 0; k < 64; ++k) {
            float hv = rows[t][k];
            #pragma unroll
            for (int j = 0; j < 16; ++j)
                acc[j] = fmaf(hv, Wm0[k * 64 + cc * 16 + j], acc[j]);
        }
        #pragma unroll
        for (int j = 0; j < 16; ++j) a1[cc * 16 + j] = fmaxf(acc[j], 0.f);
    }
    #pragma unroll
    for (int k = 0; k < 64; ++k) rows[t][k] = a1[k];

    float a2[32];
    #pragma unroll
    for (int cc = 0; cc < 2; ++cc) {
        float acc[16];
        #pragma unroll
        for (int j = 0; j < 16; ++j) acc[j] = bm1[cc * 16 + j];
        for (int k = 0; k < 64; ++k) {
            float hv = rows[t][k];
            #pragma unroll
            for (int j = 0; j < 16; ++j)
                acc[j] = fmaf(hv, Wm1[k * 32 + cc * 16 + j], acc[j]);
        }
        #pragma unroll
        for (int j = 0; j < 16; ++j) a2[cc * 16 + j] = fmaxf(acc[j], 0.f);
    }
    float z = bm2[0];
    #pragma unroll
    for (int k = 0; k < 32; ++k) z = fmaf(a2[k], Wm2[k], z);
    out[n] = 1.0f / (1.0f + __expf(-z));
}

extern "C" void kernel_launch(void* const* d_in, const int* in_sizes, int n_in,
                              void* d_out, int out_size, void* d_ws, size_t ws_size,
                              hipStream_t stream) {
    const float* x   = (const float*)d_in[0];
    const int*   src = (const int*)d_in[1];
    const int*   dst = (const int*)d_in[2];
    const float* W0  = (const float*)d_in[3];
    const float* b0  = (const float*)d_in[4];
    const float* W1  = (const float*)d_in[5];
    const float* b1  = (const float*)d_in[6];
    const float* g0  = (const float*)d_in[7];
    const float* be0 = (const float*)d_in[8];
    const float* g1  = (const float*)d_in[9];
    const float* be1 = (const float*)d_in[10];
    const float* Wm0 = (const float*)d_in[11];
    const float* bm0 = (const float*)d_in[12];
    const float* Wm1 = (const float*)d_in[13];
    const float* bm1 = (const float*)d_in[14];
    const float* Wm2 = (const float*)d_in[15];
    const float* bm2 = (const float*)d_in[16];

    int n = in_sizes[0] / 4;
    int e = in_sizes[1];
    float* out = (float*)d_out;

    char* ws = (char*)d_ws;
    auto alignup = [](size_t v) { return (v + 255) & ~(size_t)255; };
    size_t o = 0;
    int*      bcnt    = (int*)(ws + o);      o += alignup(256 * 4);
    int*      boff    = (int*)(ws + o);      o += alignup(257 * 4);
    int*      gcur    = (int*)(ws + o);      o += alignup(256 * 4);
    float*    stats   = (float*)(ws + o);    o += alignup(256 * 4);
    int*      row_ptr = (int*)(ws + o);      o += alignup((size_t)(n + 1) * 4);
    float*    dinv    = (float*)(ws + o);    o += alignup((size_t)n * 4);
    unsigned* bedges  = (unsigned*)(ws + o); o += alignup((size_t)e * 4);
    unsigned* csr     = (unsigned*)(ws + o); o += alignup((size_t)e * 4);
    __half*   A       = (__half*)(ws + o);   o += alignup((size_t)n * 64 * 2);
    float*    B       = (float*)(ws + o);

    int nb     = (n + BSZ - 1) >> BSH;        // 196 buckets for n=100k (requires n<=131072)
    int gN4    = (n + 3) / 4;
    int ntiles = (e + T1 - 1) / T1;
    int gMLP   = (n + 63) / 64;
    int gAGG   = (n + 63) / 64;               // one block per 64-node group

    (void)hipMemsetAsync(bcnt, 0, 256 * 4, stream);
    (void)hipMemsetAsync(stats, 0, 256 * 4, stream);

    // ---- CSR build (bucketed, once, reused by both layers) ----
    k_bhist<<<512, 256, 0, stream>>>(dst, bcnt, e);
    k_bscan<<<1, 256, 0, stream>>>(bcnt, boff, gcur, row_ptr, nb, n, e);
    k_bucket<<<ntiles, 256, 0, stream>>>(src, dst, gcur, bedges, e);
    k_build<<<nb, 256, 0, stream>>>(bedges, boff, row_ptr, csr, dinv, n);

    // ---- layer 1 ----
    k_lin0<<<gN4, 256, 0, stream>>>(x, W0, dinv, A, n);
    k_aggr<<<gAGG, 256, 0, stream>>>(row_ptr, csr, A, dinv, b0, B, stats, n);

    // ---- layer 2 (BN0+ReLU fused into lin1) ----
    k_lin1<<<2048, 256, 0, stream>>>(B, W1, dinv, stats, g0, be0, A, n);
    k_aggr<<<gAGG, 256, 0, stream>>>(row_ptr, csr, A, dinv, b1, B, stats + 128, n);

    // ---- MLP head (BN1+ReLU fused) ----
    k_mlp<<<gMLP, 64, 0, stream>>>(B, stats + 128, g1, be1,
                                   Wm0, bm0, Wm1, bm1, Wm2, bm2, out, n);
}